// Round 7
// baseline (276.169 us; speedup 1.0000x reference)
//
#include <hip/hip_runtime.h>
#include <cstdint>
#include <cstddef>

typedef unsigned short u16t;
typedef __bf16 bf16x8_t __attribute__((ext_vector_type(8)));
typedef float f32x4_t __attribute__((ext_vector_type(4)));

#define MFMA_BF16 __builtin_amdgcn_mfma_f32_16x16x32_bf16

__device__ __forceinline__ u16t f2bf(float f) {
    uint32_t u = __builtin_bit_cast(uint32_t, f);
    u += 0x7fffu + ((u >> 16) & 1u);   // RNE
    return (u16t)(u >> 16);
}

__device__ __forceinline__ uint32_t pk2bf(float a, float b) {
    return (uint32_t)f2bf(a) | ((uint32_t)f2bf(b) << 16);
}

__device__ __forceinline__ float bflo(uint32_t u) {
    return __builtin_bit_cast(float, u << 16);
}
__device__ __forceinline__ float bfhi(uint32_t u) {
    return __builtin_bit_cast(float, u & 0xffff0000u);
}

__device__ __forceinline__ bf16x8_t ld_frag(const u16t* p) {
    return __builtin_bit_cast(bf16x8_t, *(const uint4*)p);
}

// async global->LDS DMA, 16 B per lane. lds base must be wave-uniform;
// lane i deposits at lds + i*16 B. Swizzling is done on the GLOBAL address.
__device__ __forceinline__ void gl_lds16(const u16t* g, u16t* l) {
    __builtin_amdgcn_global_load_lds(
        (const __attribute__((address_space(1))) void*)g,
        (__attribute__((address_space(3))) void*)l, 16, 0, 0);
}

// ---------------- cast f32 -> bf16, 4 elems/thread ----------------
__global__ void cast_bf16_kernel(const float* __restrict__ src, u16t* __restrict__ dst, int n4) {
    int i = blockIdx.x * blockDim.x + threadIdx.x;
    if (i >= n4) return;
    float4 v = ((const float4*)src)[i];
    uint2 o;
    o.x = pk2bf(v.x, v.y);
    o.y = pk2bf(v.z, v.w);
    ((uint2*)dst)[i] = o;
}

// ---------------- transpose + cast: W[K][N] f32 -> Wt[N][K] bf16 ----------------
__global__ void transpose_cast_kernel(const float* __restrict__ W, u16t* __restrict__ Wt,
                                      int K, int N) {
    __shared__ float tile[32][33];
    int n0 = blockIdx.x * 32, k0 = blockIdx.y * 32;
    int tx = threadIdx.x, ty = threadIdx.y;
    for (int i = ty; i < 32; i += 8)
        tile[i][tx] = W[(size_t)(k0 + i) * N + n0 + tx];
    __syncthreads();
    for (int i = ty; i < 32; i += 8)
        Wt[(size_t)(n0 + i) * K + k0 + tx] = f2bf(tile[tx][i]);
}

// ---------------- GEMM v2: C = A[M][K]bf16 @ Bt[N][K]^T, tile 128x64 ----------------
// (unchanged from R6)
__global__ __launch_bounds__(256) void gemm_bf16_kernel(
    const u16t* __restrict__ A, const u16t* __restrict__ Bt,
    int K, void* __restrict__ outp, const float* __restrict__ bias,
    int mode, float oscale)
{
    __shared__ __align__(16) u16t As[2][128 * 64];
    __shared__ __align__(16) u16t Bs[2][64 * 64];
    const int bm = blockIdx.y * 128, bn = blockIdx.x * 64;
    const int tid = threadIdx.x;
    const int wave = tid >> 6, lane = tid & 63;
    const int wm = wave & 1, wn = wave >> 1;
    const int quad = lane >> 4, l16 = lane & 15;

    const int l8r = lane >> 3, l8c = lane & 7;
    const int cgx = (l8c ^ l8r) * 8;

    f32x4_t acc[4][2];
#pragma unroll
    for (int i = 0; i < 4; ++i)
#pragma unroll
        for (int j = 0; j < 2; ++j) acc[i][j] = (f32x4_t){0.f, 0.f, 0.f, 0.f};

    const int nk = K >> 6;

#pragma unroll
    for (int it = 0; it < 4; ++it) {
        int rb = wave * 32 + it * 8;
        gl_lds16(&A[(size_t)(bm + rb + l8r) * K + cgx], &As[0][rb * 64]);
    }
#pragma unroll
    for (int it = 0; it < 2; ++it) {
        int rb = wave * 16 + it * 8;
        gl_lds16(&Bt[(size_t)(bn + rb + l8r) * K + cgx], &Bs[0][rb * 64]);
    }

    for (int ki = 0; ki < nk; ++ki) {
        const int buf = ki & 1;
        __syncthreads();

        if (ki + 1 < nk) {
            const int kc = (ki + 1) << 6;
#pragma unroll
            for (int it = 0; it < 4; ++it) {
                int rb = wave * 32 + it * 8;
                gl_lds16(&A[(size_t)(bm + rb + l8r) * K + kc + cgx], &As[buf ^ 1][rb * 64]);
            }
#pragma unroll
            for (int it = 0; it < 2; ++it) {
                int rb = wave * 16 + it * 8;
                gl_lds16(&Bt[(size_t)(bn + rb + l8r) * K + kc + cgx], &Bs[buf ^ 1][rb * 64]);
            }
        }

#pragma unroll
        for (int ks = 0; ks < 2; ++ks) {
            bf16x8_t af[4], bfv[2];
#pragma unroll
            for (int i = 0; i < 4; ++i) {
                int r = wm * 64 + i * 16 + l16;
                af[i] = ld_frag(&As[buf][r * 64 + (((ks * 4 + quad) ^ (r & 7)) * 8)]);
            }
#pragma unroll
            for (int j = 0; j < 2; ++j) {
                int r = wn * 32 + j * 16 + l16;
                bfv[j] = ld_frag(&Bs[buf][r * 64 + (((ks * 4 + quad) ^ (r & 7)) * 8)]);
            }
#pragma unroll
            for (int i = 0; i < 4; ++i)
#pragma unroll
                for (int j = 0; j < 2; ++j)
                    acc[i][j] = MFMA_BF16(af[i], bfv[j], acc[i][j], 0, 0, 0);
        }
    }

    if (mode == 3) {
        float* out = (float*)outp;
#pragma unroll
        for (int j = 0; j < 2; ++j) {
            int c = bn + wn * 32 + j * 16 + l16;
            float b = bias[c];
#pragma unroll
            for (int i = 0; i < 4; ++i) {
                int rb = bm + wm * 64 + i * 16 + quad * 4;
#pragma unroll
                for (int r = 0; r < 4; ++r)
                    out[(size_t)(rb + r) * 1024 + c] = acc[i][j][r] + b;
            }
        }
    } else if (mode == 2) {
        u16t* out = (u16t*)outp;
#pragma unroll
        for (int i = 0; i < 4; ++i)
#pragma unroll
            for (int j = 0; j < 2; ++j) {
                int rb = bm + wm * 64 + i * 16 + quad * 4;
                int c = bn + wn * 32 + j * 16 + l16;
                int h = c >> 7, d = c & 127;
                uint2 pk;
                pk.x = pk2bf(acc[i][j][0], acc[i][j][1]);
                pk.y = pk2bf(acc[i][j][2], acc[i][j][3]);
                *(uint2*)&out[((size_t)h * 128 + d) * 4096 + rb] = pk;
            }
    } else {
        u16t* out = (u16t*)outp;
#pragma unroll
        for (int i = 0; i < 4; ++i)
#pragma unroll
            for (int j = 0; j < 2; ++j) {
                int rb = bm + wm * 64 + i * 16 + quad * 4;
                int c = bn + wn * 32 + j * 16 + l16;
                int h = c >> 7, d = c & 127;
#pragma unroll
                for (int r = 0; r < 4; ++r)
                    out[((size_t)h * 4096 + rb + r) * 128 + d] = f2bf(acc[i][j][r] * oscale);
            }
    }
}

// ---------------- flash attention v4: K-split x2, BN=32, 4 blocks/CU ----------------
// grid (8 heads, 64 q-blocks, 2 k-splits) = 1024 blocks; 36 KB LDS -> 4 blocks/CU
// = 16 waves/CU, desynchronized blocks overlap MFMA and VALU phases (m114).
// Max-free softmax => partials combine by plain addition (no rescale):
// each split writes unnormalized O^T (bf16) + l (f32); combine_kernel normalizes.
// LDS elem offsets: Ks dbuf @0/@4096 (32 keys x 128 d), Vs dbuf @8192/@12288
// (128 d x 32 j, row stride 32), Ps @16384 (64 q x 32 j).
// Narrow (32-elem) rows use chunk swizzle ^((row>>1)&3) => <=2-way (free).
// Waves 0-1 DMA the K tile, waves 2-3 the V tile (4 issues each).
__global__ __launch_bounds__(256) void flash_kernel(
    const u16t* __restrict__ Qh, const u16t* __restrict__ Kh,
    const u16t* __restrict__ Vtg, u16t* __restrict__ Op0,
    u16t* __restrict__ Op1, float* __restrict__ lp)
{
    extern __shared__ __align__(16) u16t smem[];
    u16t* Ps = smem + 16384;

    const int h = blockIdx.x;            // linear%8 == h -> head pinned to one XCD
    const int q0 = blockIdx.y * 64;
    const int z = blockIdx.z;
    const int tid = threadIdx.x;
    const int wave = tid >> 6, lane = tid & 63;
    const int quad = lane >> 4, l16 = lane & 15;

    const u16t* Kg = Kh + (size_t)h * 4096 * 128 + (size_t)z * 2048 * 128;
    const u16t* Vg = Vtg + (size_t)h * 128 * 4096 + z * 2048;

    // ---- prologue: stage Q (64x128) into smem[0..8192), build qf ----
    {
        const u16t* Qg = Qh + ((size_t)h * 4096 + q0) * 128;
        const int sr = tid >> 4, c8 = tid & 15;
#pragma unroll
        for (int it = 0; it < 4; ++it) {
            int r = sr + it * 16;
            uint4 v = *(const uint4*)&Qg[r * 128 + c8 * 8];
            *(uint4*)&smem[r * 128 + ((c8 ^ (r & 15)) * 8)] = v;
        }
    }
    __syncthreads();
    bf16x8_t qf[4];
    {
        int r = wave * 16 + l16;
#pragma unroll
        for (int ks = 0; ks < 4; ++ks)
            qf[ks] = ld_frag(&smem[r * 128 + (((ks * 4 + quad) ^ (r & 15)) * 8)]);
    }
    __syncthreads();                     // all waves done reading Q before DMA overwrites

    // DMA lane roles
    const int rK = lane >> 4, cK = lane & 15;   // K: 4 rows x 16 chunks / issue
    const int rV = lane >> 2, cV = lane & 3;    // V: 16 rows x 4 chunks / issue
    const bool kRole = wave < 2;
    const int wh = wave & 1;             // 0/1 within role pair

    // ---- first tiles (j0 = 0) into buffer 0 ----
    if (kRole) {
#pragma unroll
        for (int it = 0; it < 4; ++it) {
            int row = wh * 16 + it * 4 + rK;
            gl_lds16(Kg + (size_t)row * 128 + ((cK ^ (row & 15)) * 8),
                     smem + (wh * 16 + it * 4) * 128);
        }
    } else {
#pragma unroll
        for (int it = 0; it < 4; ++it) {
            int row = wh * 64 + it * 16 + rV;
            gl_lds16(Vg + (size_t)row * 4096 + ((cV ^ ((row >> 1) & 3)) * 8),
                     smem + 8192 + (wh * 64 + it * 16) * 32);
        }
    }

    f32x4_t O[8];
#pragma unroll
    for (int dt = 0; dt < 8; ++dt) O[dt] = (f32x4_t){0.f, 0.f, 0.f, 0.f};
    float lsum = 0.f;
    const int prow = wave * 16 + l16;    // wave-private P^T row (this lane's q)
    const int psw = (prow >> 1) & 3;     // P/V narrow-row swizzle bits

    for (int kb = 0; kb < 64; ++kb) {
        const int bo  = (kb & 1) * 4096;
        const int bon = 4096 - bo;
        __syncthreads();                 // drains own DMA (vmcnt 0) + syncs block

        if (kb < 63) {                   // DMA next tile into buf^1
            const int j0n = (kb + 1) * 32;
            if (kRole) {
#pragma unroll
                for (int it = 0; it < 4; ++it) {
                    int row = wh * 16 + it * 4 + rK;
                    gl_lds16(Kg + (size_t)(j0n + row) * 128 + ((cK ^ (row & 15)) * 8),
                             smem + bon + (wh * 16 + it * 4) * 128);
                }
            } else {
#pragma unroll
                for (int it = 0; it < 4; ++it) {
                    int row = wh * 64 + it * 16 + rV;
                    gl_lds16(Vg + (size_t)row * 4096 + j0n + ((cV ^ ((row >> 1) & 3)) * 8),
                             smem + 8192 + bon + (wh * 64 + it * 16) * 32);
                }
            }
        }

        const u16t* Ks = smem + bo;
        const u16t* Vs = smem + 8192 + bo;

        // ---- QK^T: S^T[jt][j=quad*4+r][q=l16] ----
        f32x4_t S[2];
#pragma unroll
        for (int jt = 0; jt < 2; ++jt) {
            S[jt] = (f32x4_t){0.f, 0.f, 0.f, 0.f};
            int rk = jt * 16 + l16;
#pragma unroll
            for (int ks = 0; ks < 4; ++ks) {
                bf16x8_t kf = ld_frag(&Ks[rk * 128 + (((ks * 4 + quad) ^ (rk & 15)) * 8)]);
                S[jt] = MFMA_BF16(kf, qf[ks], S[jt], 0, 0, 0);
            }
        }

        // ---- max-free softmax: P^T = exp2(S^T), b64 writes to own row ----
#pragma unroll
        for (int jt = 0; jt < 2; ++jt) {
            float e0 = __builtin_amdgcn_exp2f(S[jt][0]);
            float e1 = __builtin_amdgcn_exp2f(S[jt][1]);
            float e2 = __builtin_amdgcn_exp2f(S[jt][2]);
            float e3 = __builtin_amdgcn_exp2f(S[jt][3]);
            lsum += (e0 + e1) + (e2 + e3);
            uint2 pk;
            pk.x = pk2bf(e0, e1);
            pk.y = pk2bf(e2, e3);
            int ch = (jt * 2 + (quad >> 1)) ^ psw;
            *(uint2*)&Ps[prow * 32 + ch * 8 + (quad & 1) * 4] = pk;
        }

        // ---- PV: O^T[d=dt*16+quad*4+r][q=l16] += V^T · P^T  (K=32 = one frag) ----
        {
            bf16x8_t pf = ld_frag(&Ps[prow * 32 + ((quad ^ psw) * 8)]);
#pragma unroll
            for (int dt = 0; dt < 8; ++dt) {
                int rv = dt * 16 + l16;
                bf16x8_t vf = ld_frag(&Vs[rv * 32 + ((quad ^ ((rv >> 1) & 3)) * 8)]);
                O[dt] = MFMA_BF16(vf, pf, O[dt], 0, 0, 0);
            }
        }
    }

    // ---- epilogue: reduce l across quads, store UNNORMALIZED partials ----
    lsum += __shfl_xor(lsum, 16, 64);
    lsum += __shfl_xor(lsum, 32, 64);
    u16t* Op = z ? Op1 : Op0;
    size_t i = (size_t)(q0 + wave * 16 + l16);
    if (quad == 0) lp[z * 32768 + i * 8 + h] = lsum;
#pragma unroll
    for (int dt = 0; dt < 8; ++dt) {
        uint2 pk;
        pk.x = pk2bf(O[dt][0], O[dt][1]);
        pk.y = pk2bf(O[dt][2], O[dt][3]);
        *(uint2*)&Op[i * 1024 + h * 128 + dt * 16 + quad * 4] = pk;
    }
}

// ---------------- combine: Oh = (O0 + O1) / (l0 + l1), 8 bf16/thread ----------------
__global__ __launch_bounds__(256) void combine_kernel(
    const u16t* __restrict__ O0, const u16t* __restrict__ O1,
    const float* __restrict__ lp, u16t* __restrict__ out)
{
    int t = blockIdx.x * blockDim.x + threadIdx.x;   // vec id, 8 elems each
    int e = t << 3;
    int i = e >> 10, h = (e >> 7) & 7;
    float inv = 1.f / (lp[i * 8 + h] + lp[32768 + i * 8 + h]);
    uint4 a = ((const uint4*)O0)[t];
    uint4 b = ((const uint4*)O1)[t];
    uint4 r;
    r.x = pk2bf((bflo(a.x) + bflo(b.x)) * inv, (bfhi(a.x) + bfhi(b.x)) * inv);
    r.y = pk2bf((bflo(a.y) + bflo(b.y)) * inv, (bfhi(a.y) + bfhi(b.y)) * inv);
    r.z = pk2bf((bflo(a.z) + bflo(b.z)) * inv, (bfhi(a.z) + bfhi(b.z)) * inv);
    r.w = pk2bf((bflo(a.w) + bflo(b.w)) * inv, (bfhi(a.w) + bfhi(b.w)) * inv);
    ((uint4*)out)[t] = r;
}

// =====================================================================
extern "C" void kernel_launch(void* const* d_in, const int* in_sizes, int n_in,
                              void* d_out, int out_size, void* d_ws, size_t ws_size,
                              hipStream_t stream)
{
    (void)in_sizes; (void)n_in; (void)out_size; (void)ws_size;
    const float* x    = (const float*)d_in[0];   // (2,2048,1024)
    const float* ctx  = (const float*)d_in[1];   // (2,2048,768)
    const float* Wq   = (const float*)d_in[2];   // (1024,1024)
    const float* Wk   = (const float*)d_in[3];   // (768,1024)
    const float* Wv   = (const float*)d_in[4];   // (768,1024)
    const float* Wout = (const float*)d_in[5];   // (1024,1024)
    const float* bout = (const float*)d_in[6];   // (1024,)
    float* out = (float*)d_out;                  // (2,2048,1024) f32

    u16t* ws = (u16t*)d_ws;                      // ~47 MB of bf16 scratch
    u16t* x_bf   = ws;                           // 4194304
    u16t* ctx_bf = x_bf + 4194304;               // 3145728
    u16t* Wqt    = ctx_bf + 3145728;             // 1048576  [N=1024][K=1024]
    u16t* Wkt    = Wqt + 1048576;                // 786432   [1024][768]
    u16t* Wvt    = Wkt + 786432;                 // 786432
    u16t* Woutt  = Wvt + 786432;                 // 1048576
    u16t* Qh     = Woutt + 1048576;              // 4194304  [8][4096][128]
    u16t* Kh     = Qh + 4194304;                 // 4194304
    u16t* Vt     = Kh + 4194304;                 // 4194304  [8][128][4096]
    // flash-phase reuse of dead projection buffers:
    u16t* Oh   = x_bf;                           // split-0 partial, then combined O
    u16t* Ohp1 = ws + 4194304;                   // split-1 partial (over ctx_bf+Wqt, dead)
    float* lp  = (float*)(ws + 8388608);         // l partials [2][4096][8] (over Wkt, dead)

    // tau * dim^-0.5 * log2(e), folded into Q so flash uses raw exp2
    constexpr float QSCALE = 1.5f * 0.08838834764831845f * 1.4426950408889634f;

    (void)hipFuncSetAttribute((const void*)flash_kernel,
                              hipFuncAttributeMaxDynamicSharedMemorySize, 36864);

    cast_bf16_kernel<<<4096, 256, 0, stream>>>(x, x_bf, 1048576);
    cast_bf16_kernel<<<3072, 256, 0, stream>>>(ctx, ctx_bf, 786432);
    transpose_cast_kernel<<<dim3(32, 32), dim3(32, 8), 0, stream>>>(Wq, Wqt, 1024, 1024);
    transpose_cast_kernel<<<dim3(32, 24), dim3(32, 8), 0, stream>>>(Wk, Wkt, 768, 1024);
    transpose_cast_kernel<<<dim3(32, 24), dim3(32, 8), 0, stream>>>(Wv, Wvt, 768, 1024);
    transpose_cast_kernel<<<dim3(32, 32), dim3(32, 8), 0, stream>>>(Wout, Woutt, 1024, 1024);

    gemm_bf16_kernel<<<dim3(16, 32), 256, 0, stream>>>(x_bf,   Wqt, 1024, Qh, nullptr, 0, QSCALE);
    gemm_bf16_kernel<<<dim3(16, 32), 256, 0, stream>>>(ctx_bf, Wkt,  768, Kh, nullptr, 0, 1.0f);
    gemm_bf16_kernel<<<dim3(16, 32), 256, 0, stream>>>(ctx_bf, Wvt,  768, Vt, nullptr, 2, 1.0f);

    flash_kernel<<<dim3(8, 64, 2), 256, 36864, stream>>>(Qh, Kh, Vt, Oh, Ohp1, lp);
    combine_kernel<<<4096, 256, 0, stream>>>(Oh, Ohp1, lp, Oh);

    gemm_bf16_kernel<<<dim3(16, 32), 256, 0, stream>>>(Oh, Woutt, 1024, out, bout, 3, 1.0f);
}

// Round 8
// 259.315 us; speedup vs baseline: 1.0650x; 1.0650x over previous
//
#include <hip/hip_runtime.h>
#include <cstdint>
#include <cstddef>

typedef unsigned short u16t;
typedef __bf16 bf16x8_t __attribute__((ext_vector_type(8)));
typedef float f32x4_t __attribute__((ext_vector_type(4)));

#define MFMA_BF16 __builtin_amdgcn_mfma_f32_16x16x32_bf16

__device__ __forceinline__ u16t f2bf(float f) {
    uint32_t u = __builtin_bit_cast(uint32_t, f);
    u += 0x7fffu + ((u >> 16) & 1u);   // RNE
    return (u16t)(u >> 16);
}

__device__ __forceinline__ uint32_t pk2bf(float a, float b) {
    return (uint32_t)f2bf(a) | ((uint32_t)f2bf(b) << 16);
}

// fast bf16x2 pack: round-half-up + single v_perm_b32 (3 VALU vs ~10 for RNE)
__device__ __forceinline__ uint32_t pk2bf_fast(float a, float b) {
    uint32_t au = __builtin_bit_cast(uint32_t, a) + 0x8000u;
    uint32_t bu = __builtin_bit_cast(uint32_t, b) + 0x8000u;
    return __builtin_amdgcn_perm(bu, au, 0x07060302u);  // {b.b3,b.b2,a.b3,a.b2}
}

__device__ __forceinline__ float bflo(uint32_t u) {
    return __builtin_bit_cast(float, u << 16);
}
__device__ __forceinline__ float bfhi(uint32_t u) {
    return __builtin_bit_cast(float, u & 0xffff0000u);
}

__device__ __forceinline__ bf16x8_t ld_frag(const u16t* p) {
    return __builtin_bit_cast(bf16x8_t, *(const uint4*)p);
}

// async global->LDS DMA, 16 B per lane. lds base must be wave-uniform;
// lane i deposits at lds + i*16 B. Swizzling is done on the GLOBAL address.
__device__ __forceinline__ void gl_lds16(const u16t* g, u16t* l) {
    __builtin_amdgcn_global_load_lds(
        (const __attribute__((address_space(1))) void*)g,
        (__attribute__((address_space(3))) void*)l, 16, 0, 0);
}

// ---------------- fused cast f32 -> bf16 for x and ctx, 4 elems/thread ----------------
__global__ void cast2_bf16_kernel(const float* __restrict__ s0, u16t* __restrict__ d0, int n0,
                                  const float* __restrict__ s1, u16t* __restrict__ d1, int n1) {
    int i = blockIdx.x * blockDim.x + threadIdx.x;
    const float* s; u16t* d;
    if (i < n0) { s = s0; d = d0; }
    else { i -= n0; if (i >= n1) return; s = s1; d = d1; }
    float4 v = ((const float4*)s)[i];
    uint2 o;
    o.x = pk2bf(v.x, v.y);
    o.y = pk2bf(v.z, v.w);
    ((uint2*)d)[i] = o;
}

// ---------------- fused transpose+cast of all 4 weights: W[K][1024] -> Wt[1024][K] ----
__global__ void transpose4_kernel(const float* __restrict__ Wq, const float* __restrict__ Wk,
                                  const float* __restrict__ Wv, const float* __restrict__ Wo,
                                  u16t* __restrict__ Wqt, u16t* __restrict__ Wkt,
                                  u16t* __restrict__ Wvt, u16t* __restrict__ Wot) {
    const int z = blockIdx.z;
    const float* W = z == 0 ? Wq : (z == 1 ? Wk : (z == 2 ? Wv : Wo));
    u16t* Wt      = z == 0 ? Wqt : (z == 1 ? Wkt : (z == 2 ? Wvt : Wot));
    const int K   = (z == 1 || z == 2) ? 768 : 1024;
    const int N = 1024;
    int n0 = blockIdx.x * 32, k0 = blockIdx.y * 32;
    if (k0 >= K) return;
    __shared__ float tile[32][33];
    int tx = threadIdx.x, ty = threadIdx.y;
    for (int i = ty; i < 32; i += 8)
        tile[i][tx] = W[(size_t)(k0 + i) * N + n0 + tx];
    __syncthreads();
    for (int i = ty; i < 32; i += 8)
        Wt[(size_t)(n0 + i) * K + k0 + tx] = f2bf(tile[tx][i]);
}

// ---------------- GEMM core: C = A[M][K]bf16 @ Bt[N][K]^T, tile 128x64 ----------------
// DMA double-buffer, one barrier per K-step.
// mode 0: bf16 head-split store out[(h*4096+row)*128+d] * oscale  (Q/K)
// mode 2: bf16 transposed store out[(h*128+d)*4096+row]           (V^T)
// mode 3: f32 store out[row*1024+c] + bias[c]                     (final)
__device__ __forceinline__ void gemm_core(
    const u16t* __restrict__ A, const u16t* __restrict__ Bt,
    int K, void* __restrict__ outp, const float* __restrict__ bias,
    int mode, float oscale, int bm, int bn)
{
    __shared__ __align__(16) u16t As[2][128 * 64];
    __shared__ __align__(16) u16t Bs[2][64 * 64];
    const int tid = threadIdx.x;
    const int wave = tid >> 6, lane = tid & 63;
    const int wm = wave & 1, wn = wave >> 1;
    const int quad = lane >> 4, l16 = lane & 15;

    const int l8r = lane >> 3, l8c = lane & 7;
    const int cgx = (l8c ^ l8r) * 8;

    f32x4_t acc[4][2];
#pragma unroll
    for (int i = 0; i < 4; ++i)
#pragma unroll
        for (int j = 0; j < 2; ++j) acc[i][j] = (f32x4_t){0.f, 0.f, 0.f, 0.f};

    const int nk = K >> 6;

#pragma unroll
    for (int it = 0; it < 4; ++it) {
        int rb = wave * 32 + it * 8;
        gl_lds16(&A[(size_t)(bm + rb + l8r) * K + cgx], &As[0][rb * 64]);
    }
#pragma unroll
    for (int it = 0; it < 2; ++it) {
        int rb = wave * 16 + it * 8;
        gl_lds16(&Bt[(size_t)(bn + rb + l8r) * K + cgx], &Bs[0][rb * 64]);
    }

    for (int ki = 0; ki < nk; ++ki) {
        const int buf = ki & 1;
        __syncthreads();

        if (ki + 1 < nk) {
            const int kc = (ki + 1) << 6;
#pragma unroll
            for (int it = 0; it < 4; ++it) {
                int rb = wave * 32 + it * 8;
                gl_lds16(&A[(size_t)(bm + rb + l8r) * K + kc + cgx], &As[buf ^ 1][rb * 64]);
            }
#pragma unroll
            for (int it = 0; it < 2; ++it) {
                int rb = wave * 16 + it * 8;
                gl_lds16(&Bt[(size_t)(bn + rb + l8r) * K + kc + cgx], &Bs[buf ^ 1][rb * 64]);
            }
        }

#pragma unroll
        for (int ks = 0; ks < 2; ++ks) {
            bf16x8_t af[4], bfv[2];
#pragma unroll
            for (int i = 0; i < 4; ++i) {
                int r = wm * 64 + i * 16 + l16;
                af[i] = ld_frag(&As[buf][r * 64 + (((ks * 4 + quad) ^ (r & 7)) * 8)]);
            }
#pragma unroll
            for (int j = 0; j < 2; ++j) {
                int r = wn * 32 + j * 16 + l16;
                bfv[j] = ld_frag(&Bs[buf][r * 64 + (((ks * 4 + quad) ^ (r & 7)) * 8)]);
            }
#pragma unroll
            for (int i = 0; i < 4; ++i)
#pragma unroll
                for (int j = 0; j < 2; ++j)
                    acc[i][j] = MFMA_BF16(af[i], bfv[j], acc[i][j], 0, 0, 0);
        }
    }

    if (mode == 3) {
        float* out = (float*)outp;
#pragma unroll
        for (int j = 0; j < 2; ++j) {
            int c = bn + wn * 32 + j * 16 + l16;
            float b = bias[c];
#pragma unroll
            for (int i = 0; i < 4; ++i) {
                int rb = bm + wm * 64 + i * 16 + quad * 4;
#pragma unroll
                for (int r = 0; r < 4; ++r)
                    out[(size_t)(rb + r) * 1024 + c] = acc[i][j][r] + b;
            }
        }
    } else if (mode == 2) {
        u16t* out = (u16t*)outp;
#pragma unroll
        for (int i = 0; i < 4; ++i)
#pragma unroll
            for (int j = 0; j < 2; ++j) {
                int rb = bm + wm * 64 + i * 16 + quad * 4;
                int c = bn + wn * 32 + j * 16 + l16;
                int h = c >> 7, d = c & 127;
                uint2 pk;
                pk.x = pk2bf(acc[i][j][0], acc[i][j][1]);
                pk.y = pk2bf(acc[i][j][2], acc[i][j][3]);
                *(uint2*)&out[((size_t)h * 128 + d) * 4096 + rb] = pk;
            }
    } else {
        u16t* out = (u16t*)outp;
#pragma unroll
        for (int i = 0; i < 4; ++i)
#pragma unroll
            for (int j = 0; j < 2; ++j) {
                int rb = bm + wm * 64 + i * 16 + quad * 4;
                int c = bn + wn * 32 + j * 16 + l16;
                int h = c >> 7, d = c & 127;
#pragma unroll
                for (int r = 0; r < 4; ++r)
                    out[((size_t)h * 4096 + rb + r) * 128 + d] = f2bf(acc[i][j][r] * oscale);
            }
    }
}

__global__ __launch_bounds__(256) void gemm_bf16_kernel(
    const u16t* __restrict__ A, const u16t* __restrict__ Bt,
    int K, void* __restrict__ outp, const float* __restrict__ bias,
    int mode, float oscale)
{
    gemm_core(A, Bt, K, outp, bias, mode, oscale, blockIdx.y * 128, blockIdx.x * 64);
}

// ---------------- fused Q/K/V projections: grid.z selects the GEMM ----------------
// 1536 blocks = 6 blocks/CU co-resident (vs 2 when launched separately) -> the
// DMA round-trip latency that stalled the standalone GEMMs is hidden by 3x waves.
__global__ __launch_bounds__(256) void qkv_kernel(
    const u16t* __restrict__ x_bf, const u16t* __restrict__ ctx_bf,
    const u16t* __restrict__ Wqt, const u16t* __restrict__ Wkt,
    const u16t* __restrict__ Wvt,
    u16t* __restrict__ Qh, u16t* __restrict__ Kh, u16t* __restrict__ Vt,
    float qscale)
{
    const int z = blockIdx.z;
    const u16t* A  = (z == 0) ? x_bf : ctx_bf;
    const u16t* Bt = (z == 0) ? Wqt : ((z == 1) ? Wkt : Wvt);
    void* outp     = (z == 0) ? (void*)Qh : ((z == 1) ? (void*)Kh : (void*)Vt);
    const int K    = (z == 0) ? 1024 : 768;
    const int mode = (z == 2) ? 2 : 0;
    const float sc = (z == 0) ? qscale : 1.0f;
    gemm_core(A, Bt, K, outp, nullptr, mode, sc, blockIdx.y * 128, blockIdx.x * 64);
}

// ---------------- flash attention v4.1: K-split x2, BN=32, 4 blocks/CU ----------------
// (R7 structure; P-pack now via pk2bf_fast: -28 VALU instr/wave-iter)
__global__ __launch_bounds__(256) void flash_kernel(
    const u16t* __restrict__ Qh, const u16t* __restrict__ Kh,
    const u16t* __restrict__ Vtg, u16t* __restrict__ Op0,
    u16t* __restrict__ Op1, float* __restrict__ lp)
{
    extern __shared__ __align__(16) u16t smem[];
    u16t* Ps = smem + 16384;

    const int h = blockIdx.x;
    const int q0 = blockIdx.y * 64;
    const int z = blockIdx.z;
    const int tid = threadIdx.x;
    const int wave = tid >> 6, lane = tid & 63;
    const int quad = lane >> 4, l16 = lane & 15;

    const u16t* Kg = Kh + (size_t)h * 4096 * 128 + (size_t)z * 2048 * 128;
    const u16t* Vg = Vtg + (size_t)h * 128 * 4096 + z * 2048;

    // ---- prologue: stage Q (64x128) into smem[0..8192), build qf ----
    {
        const u16t* Qg = Qh + ((size_t)h * 4096 + q0) * 128;
        const int sr = tid >> 4, c8 = tid & 15;
#pragma unroll
        for (int it = 0; it < 4; ++it) {
            int r = sr + it * 16;
            uint4 v = *(const uint4*)&Qg[r * 128 + c8 * 8];
            *(uint4*)&smem[r * 128 + ((c8 ^ (r & 15)) * 8)] = v;
        }
    }
    __syncthreads();
    bf16x8_t qf[4];
    {
        int r = wave * 16 + l16;
#pragma unroll
        for (int ks = 0; ks < 4; ++ks)
            qf[ks] = ld_frag(&smem[r * 128 + (((ks * 4 + quad) ^ (r & 15)) * 8)]);
    }
    __syncthreads();                     // all waves done reading Q before DMA overwrites

    // DMA lane roles
    const int rK = lane >> 4, cK = lane & 15;   // K: 4 rows x 16 chunks / issue
    const int rV = lane >> 2, cV = lane & 3;    // V: 16 rows x 4 chunks / issue
    const bool kRole = wave < 2;
    const int wh = wave & 1;

    // ---- first tiles (j0 = 0) into buffer 0 ----
    if (kRole) {
#pragma unroll
        for (int it = 0; it < 4; ++it) {
            int row = wh * 16 + it * 4 + rK;
            gl_lds16(Kg + (size_t)row * 128 + ((cK ^ (row & 15)) * 8),
                     smem + (wh * 16 + it * 4) * 128);
        }
    } else {
#pragma unroll
        for (int it = 0; it < 4; ++it) {
            int row = wh * 64 + it * 16 + rV;
            gl_lds16(Vg + (size_t)row * 4096 + ((cV ^ ((row >> 1) & 3)) * 8),
                     smem + 8192 + (wh * 64 + it * 16) * 32);
        }
    }

    f32x4_t O[8];
#pragma unroll
    for (int dt = 0; dt < 8; ++dt) O[dt] = (f32x4_t){0.f, 0.f, 0.f, 0.f};
    float lsum = 0.f;
    const int prow = wave * 16 + l16;
    const int psw = (prow >> 1) & 3;

    for (int kb = 0; kb < 64; ++kb) {
        const int bo  = (kb & 1) * 4096;
        const int bon = 4096 - bo;
        __syncthreads();

        if (kb < 63) {
            const int j0n = (kb + 1) * 32;
            if (kRole) {
#pragma unroll
                for (int it = 0; it < 4; ++it) {
                    int row = wh * 16 + it * 4 + rK;
                    gl_lds16(Kg + (size_t)(j0n + row) * 128 + ((cK ^ (row & 15)) * 8),
                             smem + bon + (wh * 16 + it * 4) * 128);
                }
            } else {
#pragma unroll
                for (int it = 0; it < 4; ++it) {
                    int row = wh * 64 + it * 16 + rV;
                    gl_lds16(Vg + (size_t)row * 4096 + j0n + ((cV ^ ((row >> 1) & 3)) * 8),
                             smem + 8192 + bon + (wh * 64 + it * 16) * 32);
                }
            }
        }

        const u16t* Ks = smem + bo;
        const u16t* Vs = smem + 8192 + bo;

        // ---- QK^T: S^T[jt][j=quad*4+r][q=l16] ----
        f32x4_t S[2];
#pragma unroll
        for (int jt = 0; jt < 2; ++jt) {
            S[jt] = (f32x4_t){0.f, 0.f, 0.f, 0.f};
            int rk = jt * 16 + l16;
#pragma unroll
            for (int ks = 0; ks < 4; ++ks) {
                bf16x8_t kf = ld_frag(&Ks[rk * 128 + (((ks * 4 + quad) ^ (rk & 15)) * 8)]);
                S[jt] = MFMA_BF16(kf, qf[ks], S[jt], 0, 0, 0);
            }
        }

        // ---- max-free softmax: P^T = exp2(S^T), fast-pack b64 writes to own row ----
#pragma unroll
        for (int jt = 0; jt < 2; ++jt) {
            float e0 = __builtin_amdgcn_exp2f(S[jt][0]);
            float e1 = __builtin_amdgcn_exp2f(S[jt][1]);
            float e2 = __builtin_amdgcn_exp2f(S[jt][2]);
            float e3 = __builtin_amdgcn_exp2f(S[jt][3]);
            lsum += (e0 + e1) + (e2 + e3);
            uint2 pk;
            pk.x = pk2bf_fast(e0, e1);
            pk.y = pk2bf_fast(e2, e3);
            int ch = (jt * 2 + (quad >> 1)) ^ psw;
            *(uint2*)&Ps[prow * 32 + ch * 8 + (quad & 1) * 4] = pk;
        }

        // ---- PV: O^T[d=dt*16+quad*4+r][q=l16] += V^T · P^T  (K=32 = one frag) ----
        {
            bf16x8_t pf = ld_frag(&Ps[prow * 32 + ((quad ^ psw) * 8)]);
#pragma unroll
            for (int dt = 0; dt < 8; ++dt) {
                int rv = dt * 16 + l16;
                bf16x8_t vf = ld_frag(&Vs[rv * 32 + ((quad ^ ((rv >> 1) & 3)) * 8)]);
                O[dt] = MFMA_BF16(vf, pf, O[dt], 0, 0, 0);
            }
        }
    }

    // ---- epilogue: reduce l across quads, store UNNORMALIZED partials ----
    lsum += __shfl_xor(lsum, 16, 64);
    lsum += __shfl_xor(lsum, 32, 64);
    u16t* Op = z ? Op1 : Op0;
    size_t i = (size_t)(q0 + wave * 16 + l16);
    if (quad == 0) lp[z * 32768 + i * 8 + h] = lsum;
#pragma unroll
    for (int dt = 0; dt < 8; ++dt) {
        uint2 pk;
        pk.x = pk2bf(O[dt][0], O[dt][1]);
        pk.y = pk2bf(O[dt][2], O[dt][3]);
        *(uint2*)&Op[i * 1024 + h * 128 + dt * 16 + quad * 4] = pk;
    }
}

// ---------------- combine: Oh = (O0 + O1) / (l0 + l1), 8 bf16/thread ----------------
__global__ __launch_bounds__(256) void combine_kernel(
    const u16t* __restrict__ O0, const u16t* __restrict__ O1,
    const float* __restrict__ lp, u16t* __restrict__ out)
{
    int t = blockIdx.x * blockDim.x + threadIdx.x;
    int e = t << 3;
    int i = e >> 10, h = (e >> 7) & 7;
    float inv = 1.f / (lp[i * 8 + h] + lp[32768 + i * 8 + h]);
    uint4 a = ((const uint4*)O0)[t];
    uint4 b = ((const uint4*)O1)[t];
    uint4 r;
    r.x = pk2bf((bflo(a.x) + bflo(b.x)) * inv, (bfhi(a.x) + bfhi(b.x)) * inv);
    r.y = pk2bf((bflo(a.y) + bflo(b.y)) * inv, (bfhi(a.y) + bfhi(b.y)) * inv);
    r.z = pk2bf((bflo(a.z) + bflo(b.z)) * inv, (bfhi(a.z) + bfhi(b.z)) * inv);
    r.w = pk2bf((bflo(a.w) + bflo(b.w)) * inv, (bfhi(a.w) + bfhi(b.w)) * inv);
    ((uint4*)out)[t] = r;
}

// =====================================================================
extern "C" void kernel_launch(void* const* d_in, const int* in_sizes, int n_in,
                              void* d_out, int out_size, void* d_ws, size_t ws_size,
                              hipStream_t stream)
{
    (void)in_sizes; (void)n_in; (void)out_size; (void)ws_size;
    const float* x    = (const float*)d_in[0];   // (2,2048,1024)
    const float* ctx  = (const float*)d_in[1];   // (2,2048,768)
    const float* Wq   = (const float*)d_in[2];   // (1024,1024)
    const float* Wk   = (const float*)d_in[3];   // (768,1024)
    const float* Wv   = (const float*)d_in[4];   // (768,1024)
    const float* Wout = (const float*)d_in[5];   // (1024,1024)
    const float* bout = (const float*)d_in[6];   // (1024,)
    float* out = (float*)d_out;                  // (2,2048,1024) f32

    u16t* ws = (u16t*)d_ws;                      // ~47 MB of bf16 scratch
    u16t* x_bf   = ws;                           // 4194304
    u16t* ctx_bf = x_bf + 4194304;               // 3145728
    u16t* Wqt    = ctx_bf + 3145728;             // 1048576  [N=1024][K=1024]
    u16t* Wkt    = Wqt + 1048576;                // 786432   [1024][768]
    u16t* Wvt    = Wkt + 786432;                 // 786432
    u16t* Woutt  = Wvt + 786432;                 // 1048576
    u16t* Qh     = Woutt + 1048576;              // 4194304  [8][4096][128]
    u16t* Kh     = Qh + 4194304;                 // 4194304
    u16t* Vt     = Kh + 4194304;                 // 4194304  [8][128][4096]
    // flash-phase reuse of dead projection buffers:
    u16t* Oh   = x_bf;                           // split-0 partial, then combined O
    u16t* Ohp1 = ws + 4194304;                   // split-1 partial (over ctx_bf+Wqt, dead)
    float* lp  = (float*)(ws + 8388608);         // l partials [2][4096][8] (over Wkt, dead)

    // tau * dim^-0.5 * log2(e), folded into Q so flash uses raw exp2
    constexpr float QSCALE = 1.5f * 0.08838834764831845f * 1.4426950408889634f;

    (void)hipFuncSetAttribute((const void*)flash_kernel,
                              hipFuncAttributeMaxDynamicSharedMemorySize, 36864);

    cast2_bf16_kernel<<<7168, 256, 0, stream>>>(x, x_bf, 1048576, ctx, ctx_bf, 786432);
    transpose4_kernel<<<dim3(32, 32, 4), dim3(32, 8), 0, stream>>>(
        Wq, Wk, Wv, Wout, Wqt, Wkt, Wvt, Woutt);

    qkv_kernel<<<dim3(16, 32, 3), 256, 0, stream>>>(
        x_bf, ctx_bf, Wqt, Wkt, Wvt, Qh, Kh, Vt, QSCALE);

    flash_kernel<<<dim3(8, 64, 2), 256, 36864, stream>>>(Qh, Kh, Vt, Oh, Ohp1, lp);
    combine_kernel<<<4096, 256, 0, stream>>>(Oh, Ohp1, lp, Oh);

    gemm_bf16_kernel<<<dim3(16, 32), 256, 0, stream>>>(Oh, Woutt, 1024, out, bout, 3, 1.0f);
}